// Round 1
// baseline (211.768 us; speedup 1.0000x reference)
//
#include <hip/hip_runtime.h>

// Problem constants (from reference): N_T=5, N_Y=N_X=32, N=1024, N_B=2, DT=1.
// Output Q: (2, 5120, 5120) fp32. Block-tridiagonal in 1024-blocks; each block
// is a 9- or 25-point stencil matrix. We store per-(b,t) A-row coefficients
// in d_ws:  Ac[i][p][o], i = b*4 + (t-1) in 0..7, p in 0..1023, o = raster
// offset index o = (dy+1)*3 + (dx+1), dx,dy in {-1,0,1}. Entry = A[p, p+off]
// (0 if neighbor outside the 32x32 grid). Center (o=4) always valid.

__device__ __forceinline__ float softplus10(float x) {
  // jax.nn.softplus(10x)/10 = (max(10x,0) + log1p(exp(-|10x|))) / 10
  float z = 10.f * x;
  return (fmaxf(z, 0.f) + log1pf(expf(-fabsf(z)))) * 0.1f;
}

__global__ __launch_bounds__(256) void decode_kernel(
    const float* __restrict__ P0, float* __restrict__ Ac) {
  int gid = blockIdx.x * 256 + threadIdx.x;
  if (gid >= 8 * 1024) return;
  int i = gid >> 10;        // 0..7  (= b*4 + tt)
  int p = gid & 1023;       // grid point
  int b = i >> 2;
  int t = (i & 3) + 1;      // original time channel 1..4
  const float* P = P0 + b * 35 * 1024;

  // kappa / m use the reference's raw-reshape axis mixing: q = p*5 + t
  int qq = p * 5 + t;
  int c  = qq >> 10;        // channel within the 5-channel group
  int r  = qq & 1023;       // spatial index within that channel
  float kap = softplus10(P[(0 + c) * 1024 + r]);
  float m1  = P[(5 + c) * 1024 + r];
  float m2  = P[(10 + c) * 1024 + r];

  // gamma / vx / vy use the proper transpose layout: channel 15+t etc., spatial p
  float g  = softplus10(P[(15 + t) * 1024 + p]);
  float vx = P[(20 + t) * 1024 + p];
  float vy = P[(25 + t) * 1024 + p];

  float H11 = g + vx * vx;
  float H22 = g + vy * vy;
  float H12 = vx * vy;   // 0.5*(H12+H21) = vx*vy

  float co[9];
  co[4] = kap * kap + 2.f * H11 + 2.f * H22;  // center
  co[5] = -H11 + 0.5f * m1;   // (+1, 0)
  co[3] = -H11 - 0.5f * m1;   // (-1, 0)
  co[7] = -H22 + 0.5f * m2;   // ( 0,+1)
  co[1] = -H22 - 0.5f * m2;   // ( 0,-1)
  co[8] = -0.5f * H12;        // (+1,+1)
  co[0] = -0.5f * H12;        // (-1,-1)
  co[2] =  0.5f * H12;        // (+1,-1)
  co[6] =  0.5f * H12;        // (-1,+1)

  int px = p & 31, py = p >> 5;
  #pragma unroll
  for (int o = 0; o < 9; o++) {
    const int dx = o % 3 - 1, dy = o / 3 - 1;
    int nx = px + dx, ny = py + dy;
    bool valid = (nx >= 0) & (nx < 32) & (ny >= 0) & (ny < 32);
    Ac[(i * 1024 + p) * 9 + o] = (o == 4) ? co[4] : (valid ? co[o] : 0.f);
  }
}

// M2[p,q] for M2 = (A+I)^2 of stencil matrix i.
__device__ __forceinline__ float m2e(const float* __restrict__ Ac, int i, int p, int q) {
  int px = p & 31, py = p >> 5, qx = q & 31, qy = q >> 5;
  float s = 0.f;
  #pragma unroll
  for (int o = 0; o < 9; o++) {
    const int dx = o % 3 - 1, dy = o / 3 - 1;
    int kx = px + dx, ky = py + dy;
    if (kx < 0 || kx > 31 || ky < 0 || ky > 31) continue;
    int k = ky * 32 + kx;
    float a = Ac[(i * 1024 + p) * 9 + o] + (o == 4 ? 1.f : 0.f);  // invM[p,k]
    int ddx = qx - kx, ddy = qy - ky;
    if (ddx < -1 || ddx > 1 || ddy < -1 || ddy > 1) continue;
    float bb = Ac[(i * 1024 + k) * 9 + (ddy + 1) * 3 + (ddx + 1)]
             + (k == q ? 1.f : 0.f);                               // invM[k,q]
    s += a * bb;
  }
  return s;
}

// (B0^T B0)[p,q] for B0 = A (stencil matrix i0).
__device__ __forceinline__ float btb(const float* __restrict__ Ac, int i0, int p, int q) {
  int px = p & 31, py = p >> 5, qx = q & 31, qy = q >> 5;
  float s = 0.f;
  #pragma unroll
  for (int o = 0; o < 9; o++) {
    const int dx = o % 3 - 1, dy = o / 3 - 1;
    int kx = px + dx, ky = py + dy;
    if (kx < 0 || kx > 31 || ky < 0 || ky > 31) continue;
    int k = ky * 32 + kx;
    // B0[k,p] = A[k, offset p-k = (-dx,-dy)] -> raster index 8-o (target p always in grid)
    float bkp = Ac[(i0 * 1024 + k) * 9 + (8 - o)];
    int ddx = qx - kx, ddy = qy - ky;
    if (ddx < -1 || ddx > 1 || ddy < -1 || ddy > 1) continue;
    float bkq = Ac[(i0 * 1024 + k) * 9 + (ddy + 1) * 3 + (ddx + 1)];
    s += bkp * bkq;
  }
  return s;
}

// grid: (5 block-cols, 5120 rows, 2 batches), 256 threads; one float4 per thread.
__global__ __launch_bounds__(256) void fill_kernel(
    const float* __restrict__ Ac, float4* __restrict__ out) {
  const int cb  = blockIdx.x;   // block-column 0..4
  const int row = blockIdx.y;   // 0..5119
  const int b   = blockIdx.z;   // 0..1
  const int tx  = threadIdx.x;  // 0..255
  const int rb  = row >> 10;
  const int p   = row & 1023;
  const int d   = cb - rb;
  const int oidx = b * 6553600 + row * 1280 + cb * 256 + tx;

  float4 v = make_float4(0.f, 0.f, 0.f, 0.f);
  if (d >= -1 && d <= 1) {
    const int q0 = tx * 4;
    const int px = p & 31, py = p >> 5;
    float rr[4] = {0.f, 0.f, 0.f, 0.f};
    if (d != 0) {
      // off-diagonal block: -0.5*(invM_i + invM_i^T), i = b*4 + min(rb,cb)
      const int i = b * 4 + (d > 0 ? rb : cb);
      #pragma unroll
      for (int j = 0; j < 4; j++) {
        int q = q0 + j;
        int dx = (q & 31) - px, dy = (q >> 5) - py;
        if (dx >= -1 && dx <= 1 && dy >= -1 && dy <= 1) {
          int o = (dy + 1) * 3 + (dx + 1);
          float s = Ac[(i * 1024 + p) * 9 + o]        // A[p,q]
                  + Ac[(i * 1024 + q) * 9 + (8 - o)]; // A[q,p]
          if (p == q) s += 2.f;                       // two identity diags
          rr[j] = -0.5f * s;
        }
      }
    } else if (rb == 0) {
      // block (0,0): B0^T B0 + I, plus 0.05 global diag
      const int i0 = b * 4;
      #pragma unroll
      for (int j = 0; j < 4; j++) {
        int q = q0 + j;
        int dx = (q & 31) - px, dy = (q >> 5) - py;
        if (dx >= -2 && dx <= 2 && dy >= -2 && dy <= 2) {
          rr[j] = btb(Ac, i0, p, q) + (p == q ? 1.05f : 0.f);
        }
      }
    } else {
      // block (i,i), i>=1: 0.5*(M2 + M2^T) (+I for i<=3) + 0.05 diag
      const int i = b * 4 + rb - 1;
      const float diagAdd = (rb <= 3 ? 1.05f : 0.05f);
      #pragma unroll
      for (int j = 0; j < 4; j++) {
        int q = q0 + j;
        int dx = (q & 31) - px, dy = (q >> 5) - py;
        if (dx >= -2 && dx <= 2 && dy >= -2 && dy <= 2) {
          float m2s = 0.5f * (m2e(Ac, i, p, q) + m2e(Ac, i, q, p));
          rr[j] = m2s + (p == q ? diagAdd : 0.f);
        }
      }
    }
    v = make_float4(rr[0], rr[1], rr[2], rr[3]);
  }
  out[oidx] = v;
}

extern "C" void kernel_launch(void* const* d_in, const int* in_sizes, int n_in,
                              void* d_out, int out_size, void* d_ws, size_t ws_size,
                              hipStream_t stream) {
  const float* params = (const float*)d_in[0];  // (2, 35, 32, 32) fp32
  float* Ac = (float*)d_ws;                     // 8*1024*9 floats = 294,912 B
  float4* out = (float4*)d_out;                 // (2, 5120, 5120) fp32

  decode_kernel<<<32, 256, 0, stream>>>(params, Ac);
  dim3 grid(5, 5120, 2);
  fill_kernel<<<grid, 256, 0, stream>>>(Ac, out);
}